// Round 5
// baseline (153.921 us; speedup 1.0000x reference)
//
#include <hip/hip_runtime.h>
#include <hip/hip_bf16.h>

// Problem constants: N tokens, D d_model, E experts, H hidden, K top-k
#define NTOK 4096
#define DM   512
#define NE   32
#define HD   128
#define TK   4

typedef unsigned short u16;
typedef unsigned int   u32;
typedef u16   u16x4 __attribute__((ext_vector_type(4)));
typedef u16   u16x8 __attribute__((ext_vector_type(8)));
typedef short short8 __attribute__((ext_vector_type(8)));
typedef float f32x4 __attribute__((ext_vector_type(4)));

__device__ __forceinline__ u16 f2bf(float f) {
    union { float f; u32 u; } v; v.f = f;
    return (u16)((v.u + 0x7FFFu + ((v.u >> 16) & 1u)) >> 16);   // RNE
}
__device__ __forceinline__ float bf2f(u16 h) {
    union { u32 u; float f; } v; v.u = ((u32)h) << 16; return v.f;
}

// ---------------- weight swizzle (no LDS -> high occupancy, deep ILP) ----------------
// fp32 [E][Kdim][Ndim] -> bf16 fragment-major:
//   frag[wl][lane][j] = in[e][32*ks + (lane>>4)*8 + j][16*nt + (lane&15)]
// W1: Kdim=512, Ndim=128, wl = e*128 + ks*8  + nt  (frags 0..4095)
// W2: Kdim=128, Ndim=512, wl = e*128 + ks*32 + nt  (frags 4096..8191)
// 1024 blocks x 256 thr; each wave handles 2 fragments (16 loads in flight).
__global__ __launch_bounds__(256) void swizzle_kernel(const float* __restrict__ w1,
                                                      const float* __restrict__ w2,
                                                      u16* __restrict__ wf1,
                                                      u16* __restrict__ wf2,
                                                      int* __restrict__ counts) {
    int tid = threadIdx.x;
    if (blockIdx.x == 0 && tid < NE) counts[tid] = 0;   // replaces memset dispatch
    int wv = tid >> 6, lane = tid & 63;
    int m = lane & 15, q = lane >> 4;
    int f0 = (blockIdx.x * 4 + wv) * 2;

    const float* in[2]; u16* outp[2]; int Nd[2];
#pragma unroll
    for (int u = 0; u < 2; ++u) {
        int w = f0 + u;
        if (w < 4096) {
            int e = w >> 7, rem = w & 127, ks = rem >> 3, nt = rem & 7;
            in[u] = w1 + (size_t)e * DM * HD + (size_t)(32 * ks + q * 8) * HD + 16 * nt + m;
            Nd[u] = HD;
            outp[u] = wf1 + (size_t)w * 512 + lane * 8;
        } else {
            int wl = w - 4096, e = wl >> 7, rem = wl & 127, ks = rem >> 5, nt = rem & 31;
            in[u] = w2 + (size_t)e * HD * DM + (size_t)(32 * ks + q * 8) * DM + 16 * nt + m;
            Nd[u] = DM;
            outp[u] = wf2 + (size_t)wl * 512 + lane * 8;
        }
    }
    float v[2][8];
#pragma unroll
    for (int u = 0; u < 2; ++u)
#pragma unroll
        for (int j = 0; j < 8; ++j) v[u][j] = in[u][(size_t)j * Nd[u]];
#pragma unroll
    for (int u = 0; u < 2; ++u) {
        u16x8 h;
#pragma unroll
        for (int j = 0; j < 8; ++j) h[j] = f2bf(v[u][j]);
        *(u16x8*)outp[u] = h;
    }
}

// ---------------- router: thread-per-dot fp64; fused x->bf16 ----------------
__global__ __launch_bounds__(256) void router_kernel(const float* __restrict__ x,
                                                     const float* __restrict__ sel,
                                                     int* __restrict__ counts,
                                                     int* __restrict__ tok_list,
                                                     float* __restrict__ gate_list,
                                                     u16* __restrict__ xbf) {
    __shared__ float  xs[16][516];                  // stride 516 breaks bank aliasing
    __shared__ double sc[16][33];
    int tid = threadIdx.x;
    int tb = blockIdx.x * 16;

    // stage x -> LDS fp32, and write xbf (bf16) on the way
#pragma unroll
    for (int rep = 0; rep < 8; ++rep) {
        int idx = rep * 1024 + tid * 4;             // element in 16x512 tile
        int row = idx >> 9, col = idx & 511;
        f32x4 v = *(const f32x4*)(x + (size_t)(tb + row) * DM + col);
        *(f32x4*)&xs[row][col] = v;
        u16x4 h;
#pragma unroll
        for (int j = 0; j < 4; ++j) h[j] = f2bf(v[j]);
        *(u16x4*)(xbf + (size_t)(tb + row) * DM + col) = h;
    }
    __syncthreads();

    // each thread: 2 independent fp64 dot products (token, expert eg / eg+16)
    int tok = tid & 15, eg = tid >> 4;
    const float* se0 = sel + (size_t)eg * DM;
    const float* se1 = sel + (size_t)(eg + 16) * DM;
    double p0a = 0.0, p0b = 0.0, p1a = 0.0, p1b = 0.0;
#pragma unroll 4
    for (int j = 0; j < DM; j += 8) {
        f32x4 xv0 = *(const f32x4*)&xs[tok][j];
        f32x4 xv1 = *(const f32x4*)&xs[tok][j + 4];
        f32x4 sa0 = *(const f32x4*)(se0 + j);
        f32x4 sa1 = *(const f32x4*)(se0 + j + 4);
        f32x4 sb0 = *(const f32x4*)(se1 + j);
        f32x4 sb1 = *(const f32x4*)(se1 + j + 4);
#pragma unroll
        for (int k = 0; k < 4; ++k) {
            p0a = fma((double)xv0[k], (double)sa0[k], p0a);
            p0b = fma((double)xv1[k], (double)sa1[k], p0b);
            p1a = fma((double)xv0[k], (double)sb0[k], p1a);
            p1b = fma((double)xv1[k], (double)sb1[k], p1b);
        }
    }
    sc[tok][eg]      = p0a + p0b;
    sc[tok][eg + 16] = p1a + p1b;
    __syncthreads();

    if (tid < 16) {
        int t = tb + tid;
        unsigned mask = 0;
        for (int k = 0; k < TK; ++k) {
            double best = -1e300; int be = 0;
            for (int e = 0; e < NE; ++e) {
                double v = sc[tid][e];
                if (!((mask >> e) & 1u) && v > best) { best = v; be = e; }
            }
            mask |= 1u << be;
            float gate = 1.0f / (1.0f + __expf(-(float)best));
            int pos = atomicAdd(&counts[be], 1);
            tok_list[(size_t)be * NTOK + pos]  = (k << 16) | t;   // slot in high bits
            gate_list[(size_t)be * NTOK + pos] = gate;
        }
    }
}

// ---------------- fused expert MLP ----------------
// per (expert, 64-token tile); GEMM1 waves split 2x2 (rows x cols), paired-k double
// buffer; GEMM2 each wave owns a distinct 128-col group, all B up-front.
__global__ __launch_bounds__(256, 2) void moe_mlp_kernel(const u16* __restrict__ xbf,
                                                         const u16* __restrict__ wf1,
                                                         const u16* __restrict__ wf2,
                                                         const int* __restrict__ counts,
                                                         const int* __restrict__ tok_list,
                                                         const float* __restrict__ gate_list,
                                                         u16* __restrict__ part,
                                                         float* __restrict__ out,
                                                         int use_part) {
    __shared__ int   s_cnt[NE];
    __shared__ int   s_ent[64];
    __shared__ float s_gate[64];
    __shared__ __align__(16) u16 Hm[64][136];       // 272B stride: 16B-aligned, ~2-way banks

    int tid = threadIdx.x;
    if (tid < NE) s_cnt[tid] = counts[tid];         // one coalesced load, not 32 serial
    __syncthreads();

    int b = blockIdx.x;
    int e = -1, t = 0, rows = 0, pre = 0;
#pragma unroll 8
    for (int ee = 0; ee < NE; ++ee) {
        int cc = s_cnt[ee];
        int nt = (cc + 63) >> 6;
        if (e < 0 && b < pre + nt) { e = ee; t = b - pre; rows = cc - t * 64; if (rows > 64) rows = 64; }
        pre += nt;
    }
    if (e < 0) return;

    if (tid < 64) {
        int base = e * NTOK + t * 64;
        bool val = tid < rows;
        s_ent[tid]  = tok_list[base + (val ? tid : 0)];
        s_gate[tid] = val ? gate_list[base + tid] : 0.0f;
    }
    __syncthreads();

    int wv = tid >> 6, lane = tid & 63, m = lane & 15, q = lane >> 4;
    int r = wv >> 1, c = wv & 1;                    // GEMM1: rows 32r..+32, cols 64c..+64
    const u16* w1f = wf1 + (size_t)e * (128 * 512);
    const u16* w2f = wf2 + (size_t)e * (128 * 512);

    const u16* a0 = xbf + (size_t)(s_ent[32 * r + m] & 0xFFFF) * DM + q * 8;
    const u16* a1 = xbf + (size_t)(s_ent[32 * r + 16 + m] & 0xFFFF) * DM + q * 8;

    // GEMM1: k-steps in pairs, double-buffered (12 loads in flight)
    short8 ab[2][2][2];                             // [buf][kk][mtile]
    short8 bb[2][2][4];                             // [buf][kk][ntile]
#pragma unroll
    for (int kk = 0; kk < 2; ++kk) {
        ab[0][kk][0] = *(const short8*)(a0 + 32 * kk);
        ab[0][kk][1] = *(const short8*)(a1 + 32 * kk);
        const u16* bp = w1f + (size_t)kk * 4096 + (size_t)(4 * c) * 512 + lane * 8;
#pragma unroll
        for (int n = 0; n < 4; ++n) bb[0][kk][n] = *(const short8*)(bp + n * 512);
    }
    f32x4 acc[2][4];
#pragma unroll
    for (int i = 0; i < 2; ++i)
#pragma unroll
        for (int n = 0; n < 4; ++n) acc[i][n] = (f32x4){0.f, 0.f, 0.f, 0.f};

#pragma unroll
    for (int kp = 0; kp < 8; ++kp) {
        int cur = kp & 1, nxt = cur ^ 1;
        if (kp < 7) {
            int ks0 = 2 * (kp + 1);
#pragma unroll
            for (int kk = 0; kk < 2; ++kk) {
                ab[nxt][kk][0] = *(const short8*)(a0 + 32 * (ks0 + kk));
                ab[nxt][kk][1] = *(const short8*)(a1 + 32 * (ks0 + kk));
                const u16* bp = w1f + (size_t)(ks0 + kk) * 4096 + (size_t)(4 * c) * 512 + lane * 8;
#pragma unroll
                for (int n = 0; n < 4; ++n) bb[nxt][kk][n] = *(const short8*)(bp + n * 512);
            }
        }
#pragma unroll
        for (int kk = 0; kk < 2; ++kk)
#pragma unroll
            for (int i = 0; i < 2; ++i)
#pragma unroll
                for (int n = 0; n < 4; ++n)
                    acc[i][n] = __builtin_amdgcn_mfma_f32_16x16x32_bf16(ab[cur][kk][i],
                                                                        bb[cur][kk][n],
                                                                        acc[i][n], 0, 0, 0);
    }

    // relu * gate -> Hm
#pragma unroll
    for (int i = 0; i < 2; ++i) {
        int rb = 32 * r + 16 * i + q * 4;
#pragma unroll
        for (int n = 0; n < 4; ++n)
#pragma unroll
            for (int rr = 0; rr < 4; ++rr)
                Hm[rb + rr][64 * c + 16 * n + m] =
                    f2bf(fmaxf(acc[i][n][rr], 0.f) * s_gate[rb + rr]);
    }

    // GEMM2: wave owns cols [128*wv, 128*wv+128); all 32 B-frags issued before barrier
    short8 cb[4][8];
#pragma unroll
    for (int ks = 0; ks < 4; ++ks) {
        const u16* bp = w2f + (size_t)(ks * 32 + wv * 8) * 512 + lane * 8;
#pragma unroll
        for (int n = 0; n < 8; ++n) cb[ks][n] = *(const short8*)(bp + n * 512);
    }
    __syncthreads();                                // Hm ready

#pragma unroll
    for (int half = 0; half < 2; ++half) {
        f32x4 acc2[2][8];
#pragma unroll
        for (int i = 0; i < 2; ++i)
#pragma unroll
            for (int n = 0; n < 8; ++n) acc2[i][n] = (f32x4){0.f, 0.f, 0.f, 0.f};
#pragma unroll
        for (int ks = 0; ks < 4; ++ks) {
            short8 h0 = *(const short8*)&Hm[32 * half + m][32 * ks + q * 8];
            short8 h1 = *(const short8*)&Hm[32 * half + 16 + m][32 * ks + q * 8];
#pragma unroll
            for (int n = 0; n < 8; ++n) {
                acc2[0][n] = __builtin_amdgcn_mfma_f32_16x16x32_bf16(h0, cb[ks][n], acc2[0][n], 0, 0, 0);
                acc2[1][n] = __builtin_amdgcn_mfma_f32_16x16x32_bf16(h1, cb[ks][n], acc2[1][n], 0, 0, 0);
            }
        }
#pragma unroll
        for (int i = 0; i < 2; ++i) {
            int rb = 32 * half + 16 * i + q * 4;
#pragma unroll
            for (int rr = 0; rr < 4; ++rr) {
                int rl = rb + rr;
                if (rl < rows) {
                    int en = s_ent[rl];
                    int tk = en & 0xFFFF, sl = en >> 16;
                    if (use_part) {
                        u16* pp = part + ((size_t)sl * NTOK + tk) * DM + 128 * wv + m;
#pragma unroll
                        for (int n = 0; n < 8; ++n) pp[16 * n] = f2bf(acc2[i][n][rr]);
                    } else {
                        float* op = out + (size_t)tk * DM + 128 * wv + m;
#pragma unroll
                        for (int n = 0; n < 8; ++n) atomicAdd(&op[16 * n], acc2[i][n][rr]);
                    }
                }
            }
        }
    }
}

// ---------------- combine: out[t][c] = sum_k part[k][t][c] ----------------
__global__ __launch_bounds__(256) void combine_kernel(const u16* __restrict__ part,
                                                      float* __restrict__ out) {
    size_t off = ((size_t)blockIdx.x * 256 + threadIdx.x) * 8;
    float s[8] = {0, 0, 0, 0, 0, 0, 0, 0};
#pragma unroll
    for (int k = 0; k < TK; ++k) {
        u16x8 p = *(const u16x8*)(part + (size_t)k * NTOK * DM + off);
#pragma unroll
        for (int j = 0; j < 8; ++j) s[j] += bf2f(p[j]);
    }
    *(f32x4*)(out + off)     = (f32x4){s[0], s[1], s[2], s[3]};
    *(f32x4*)(out + off + 4) = (f32x4){s[4], s[5], s[6], s[7]};
}

extern "C" void kernel_launch(void* const* d_in, const int* in_sizes, int n_in,
                              void* d_out, int out_size, void* d_ws, size_t ws_size,
                              hipStream_t stream) {
    const float* x   = (const float*)d_in[0];   // [N, D]
    const float* sel = (const float*)d_in[1];   // [E, D]
    const float* w1  = (const float*)d_in[2];   // [E, D, H]
    const float* w2  = (const float*)d_in[3];   // [E, H, D]
    float* out = (float*)d_out;                 // [N, D]

    char* ws = (char*)d_ws;
    int*   counts    = (int*)(ws);                                   // 256B
    int*   tok_list  = (int*)(ws + 2048);                            // 512KB (slot<<16 | tok)
    float* gate_list = (float*)(ws + 2048 + (size_t)NE * NTOK * 4);  // 512KB
    u16*   xbf  = (u16*)(ws + 2048 + (size_t)NE * NTOK * 8);         // 4MB
    u16*   wf1  = xbf + (size_t)NTOK * DM;                           // 4MB
    u16*   wf2  = wf1 + (size_t)NE * HD * DM;                        // 4MB
    u16*   part = wf2 + (size_t)NE * HD * DM;                        // 16.8MB (optional)

    size_t need = 2048 + (size_t)NE * NTOK * 8 + (size_t)NTOK * DM * 2
                + 2 * (size_t)NE * HD * DM * 2 + (size_t)TK * NTOK * DM * 2;
    int use_part = (ws_size >= need) ? 1 : 0;

    if (!use_part)
        hipMemsetAsync(d_out, 0, (size_t)NTOK * DM * sizeof(float), stream);

    swizzle_kernel<<<1024, 256, 0, stream>>>(w1, w2, wf1, wf2, counts);
    router_kernel<<<NTOK / 16, 256, 0, stream>>>(x, sel, counts, tok_list, gate_list, xbf);
    moe_mlp_kernel<<<288, 256, 0, stream>>>(xbf, wf1, wf2, counts, tok_list, gate_list,
                                            part, out, use_part);
    if (use_part)
        combine_kernel<<<NTOK * DM / 8 / 256, 256, 0, stream>>>(part, out);
}